// Round 2
// baseline (635.347 us; speedup 1.0000x reference)
//
#include <hip/hip_runtime.h>
#include <hip/hip_bf16.h>

#define SEQ   16384
#define DIM   2048
#define CHUNK 128
#define NCHUNK (SEQ / CHUNK)   // 128

typedef __attribute__((ext_vector_type(8))) short  short8;
typedef __attribute__((ext_vector_type(4))) short  short4v;
typedef __attribute__((ext_vector_type(4))) float  floatx4;

static __device__ __forceinline__ float bf2f(short s) {
    return __uint_as_float(((unsigned)(unsigned short)s) << 16);
}
static __device__ __forceinline__ short f2bf(float f) {
    unsigned u = __float_as_uint(f);
    u += 0x7fff + ((u >> 16) & 1);   // RNE
    return (short)(u >> 16);
}

// ---------- fp32 -> bf16 cast, float4 vectorized ----------
__global__ void cast_kernel(const float* __restrict__ in, short* __restrict__ out, int n4) {
    int i = blockIdx.x * blockDim.x + threadIdx.x;
    if (i >= n4) return;
    float4 v = ((const float4*)in)[i];
    short4v s;
    s.x = f2bf(v.x); s.y = f2bf(v.y); s.z = f2bf(v.z); s.w = f2bf(v.w);
    ((short4v*)out)[i] = s;
}

// ---------- bf16 GEMM, C[m][n] = sum_k A[m][k]*B[n][k]  (both K-contiguous) ----------
// 128x128 tile, BK=32, 256 threads = 4 waves. Double-buffered LDS: prefetch for
// iter k+1 is issued AFTER the barrier, so it overlaps iter-k ds_read+MFMA and
// is drained by the NEXT barrier's vmcnt(0) — one full iter of latency hiding.
template<int FUSE>
__global__ __launch_bounds__(256, 2)
void gemm_bt(const short* __restrict__ A, const short* __restrict__ B,
             short* __restrict__ Cbf, float* __restrict__ Cf,
             const float* __restrict__ xs, const float* __restrict__ dskip)
{
    constexpr int K = DIM;
    constexpr int ITERS = K / 32;
    __shared__ alignas(16) short As[2][128 * 32];
    __shared__ alignas(16) short Bs[2][128 * 32];

    const int tid = threadIdx.x;
    const int m0  = blockIdx.y * 128;
    const int n0  = blockIdx.x * 128;

    // staging: 512 chunks of 16B per tile, 2 per thread per operand
    const int c0 = tid, c1 = tid + 256;
    const short* ga0 = A + (size_t)(m0 + (c0 >> 2)) * K + (c0 & 3) * 8;
    const short* ga1 = A + (size_t)(m0 + (c1 >> 2)) * K + (c1 & 3) * 8;
    const short* gb0 = B + (size_t)(n0 + (c0 >> 2)) * K + (c0 & 3) * 8;
    const short* gb1 = B + (size_t)(n0 + (c1 >> 2)) * K + (c1 & 3) * 8;

    const int lane = tid & 63;
    const int wv   = tid >> 6;
    const int wm   = (wv >> 1) * 64;
    const int wn   = (wv & 1) * 64;
    const int l16  = lane & 15;
    const int quad = lane >> 4;

    floatx4 acc[4][4] = {};

    // prologue: stage tile 0 into buffer 0
    __builtin_amdgcn_global_load_lds(ga0, &As[0][c0 * 8], 16, 0, 0);
    __builtin_amdgcn_global_load_lds(ga1, &As[0][c1 * 8], 16, 0, 0);
    __builtin_amdgcn_global_load_lds(gb0, &Bs[0][c0 * 8], 16, 0, 0);
    __builtin_amdgcn_global_load_lds(gb1, &Bs[0][c1 * 8], 16, 0, 0);

    for (int it = 0; it < ITERS; ++it) {
        const int cur = it & 1;
        __syncthreads();   // drains prefetch for buffer `cur` (vmcnt(0) before s_barrier)

        if (it + 1 < ITERS) {   // uniform branch
            const int kk = (it + 1) * 32;
            const int nxt = cur ^ 1;
            __builtin_amdgcn_global_load_lds(ga0 + kk, &As[nxt][c0 * 8], 16, 0, 0);
            __builtin_amdgcn_global_load_lds(ga1 + kk, &As[nxt][c1 * 8], 16, 0, 0);
            __builtin_amdgcn_global_load_lds(gb0 + kk, &Bs[nxt][c0 * 8], 16, 0, 0);
            __builtin_amdgcn_global_load_lds(gb1 + kk, &Bs[nxt][c1 * 8], 16, 0, 0);
        }

        short8 aV[4], bV[4];
        #pragma unroll
        for (int i = 0; i < 4; i++)
            aV[i] = *(const short8*)&As[cur][(wm + i * 16 + l16) * 32 + quad * 8];
        #pragma unroll
        for (int i = 0; i < 4; i++)
            bV[i] = *(const short8*)&Bs[cur][(wn + i * 16 + l16) * 32 + quad * 8];

        #pragma unroll
        for (int mi = 0; mi < 4; mi++)
            #pragma unroll
            for (int ni = 0; ni < 4; ni++)
                acc[mi][ni] = __builtin_amdgcn_mfma_f32_16x16x32_bf16(
                    aV[mi], bV[ni], acc[mi][ni], 0, 0, 0);
        // no trailing barrier: buffer cur^1 is only overwritten after the next
        // top-of-loop barrier, and ds_reads from it completed before that barrier
    }

    // epilogue: C tile element (row = quad*4 + r, col = l16) per 16x16 frag
    if (FUSE == 0) {
        #pragma unroll
        for (int mi = 0; mi < 4; mi++) {
            int rb = m0 + wm + mi * 16 + quad * 4;
            #pragma unroll
            for (int ni = 0; ni < 4; ni++) {
                int cc = n0 + wn + ni * 16 + l16;
                #pragma unroll
                for (int r = 0; r < 4; r++)
                    Cbf[(size_t)(rb + r) * DIM + cc] = f2bf(acc[mi][ni][r]);
            }
        }
    } else {
        float dsk[4];
        #pragma unroll
        for (int ni = 0; ni < 4; ni++) dsk[ni] = dskip[n0 + wn + ni * 16 + l16];
        #pragma unroll
        for (int mi = 0; mi < 4; mi++) {
            int rb = m0 + wm + mi * 16 + quad * 4;
            #pragma unroll
            for (int ni = 0; ni < 4; ni++) {
                int cc = n0 + wn + ni * 16 + l16;
                #pragma unroll
                for (int r = 0; r < 4; r++) {
                    size_t idx = (size_t)(rb + r) * DIM + cc;
                    Cf[idx] = acc[mi][ni][r] + xs[idx] * dsk[ni];
                }
            }
        }
    }
}

// ---------- scan pass 1: per-chunk local final state (zero init) ----------
// 4 channels/thread, short4 loads; grid (DIM/1024, NCHUNK) = (2,128)
__global__ void scan_pass1(const short* __restrict__ bx, const float* __restrict__ lam,
                           float* __restrict__ blockLast)
{
    int n     = blockIdx.x * 1024 + threadIdx.x * 4;
    int chunk = blockIdx.y;
    float4 lmv = *(const float4*)(lam + n);
    float lm[4] = {lmv.x, lmv.y, lmv.z, lmv.w};
    float h[4]  = {0.f, 0.f, 0.f, 0.f};
    const short* p = bx + (size_t)chunk * CHUNK * DIM + n;
    #pragma unroll 4
    for (int i = 0; i < CHUNK; i++) {
        short4v v = *(const short4v*)(p + (size_t)i * DIM);
        h[0] = fmaf(lm[0], h[0], bf2f(v.x));
        h[1] = fmaf(lm[1], h[1], bf2f(v.y));
        h[2] = fmaf(lm[2], h[2], bf2f(v.z));
        h[3] = fmaf(lm[3], h[3], bf2f(v.w));
    }
    *(float4*)(blockLast + (size_t)chunk * DIM + n) = make_float4(h[0], h[1], h[2], h[3]);
}

// ---------- scan pass 2: exclusive prefix over chunks (in place) ----------
__global__ void scan_pass2(float* __restrict__ blockLast, const float* __restrict__ lam)
{
    int n = blockIdx.x * 1024 + threadIdx.x * 4;
    float4 lmv = *(const float4*)(lam + n);
    float p0 = lmv.x, p1 = lmv.y, p2 = lmv.z, p3 = lmv.w;
    #pragma unroll
    for (int i = 0; i < 7; i++) { p0 *= p0; p1 *= p1; p2 *= p2; p3 *= p3; } // lam^128
    float c[4] = {0.f, 0.f, 0.f, 0.f};
    for (int ch = 0; ch < NCHUNK; ch++) {
        float* q = blockLast + (size_t)ch * DIM + n;
        float4 t = *(const float4*)q;
        *(float4*)q = make_float4(c[0], c[1], c[2], c[3]);
        c[0] = fmaf(p0, c[0], t.x);
        c[1] = fmaf(p1, c[1], t.y);
        c[2] = fmaf(p2, c[2], t.z);
        c[3] = fmaf(p3, c[3], t.w);
    }
}

// ---------- scan pass 3: apply carry, write hs (bf16, in place over bx) ----------
__global__ void scan_pass3(short* __restrict__ bxh, const float* __restrict__ lam,
                           const float* __restrict__ carry)
{
    int n     = blockIdx.x * 1024 + threadIdx.x * 4;
    int chunk = blockIdx.y;
    float4 lmv = *(const float4*)(lam + n);
    float4 cv  = *(const float4*)(carry + (size_t)chunk * DIM + n);
    float lm[4] = {lmv.x, lmv.y, lmv.z, lmv.w};
    float h[4]  = {cv.x, cv.y, cv.z, cv.w};
    short* p = bxh + (size_t)chunk * CHUNK * DIM + n;
    #pragma unroll 4
    for (int i = 0; i < CHUNK; i++) {
        short4v v = *(const short4v*)(p + (size_t)i * DIM);
        h[0] = fmaf(lm[0], h[0], bf2f(v.x));
        h[1] = fmaf(lm[1], h[1], bf2f(v.y));
        h[2] = fmaf(lm[2], h[2], bf2f(v.z));
        h[3] = fmaf(lm[3], h[3], bf2f(v.w));
        short4v o;
        o.x = f2bf(h[0]); o.y = f2bf(h[1]); o.z = f2bf(h[2]); o.w = f2bf(h[3]);
        *(short4v*)(p + (size_t)i * DIM) = o;
    }
}

extern "C" void kernel_launch(void* const* d_in, const int* in_sizes, int n_in,
                              void* d_out, int out_size, void* d_ws, size_t ws_size,
                              hipStream_t stream)
{
    const float* xs    = (const float*)d_in[0];
    const float* lam   = (const float*)d_in[1];
    const float* w_in  = (const float*)d_in[2];
    const float* c_out = (const float*)d_in[3];
    const float* dskip = (const float*)d_in[4];
    float* out = (float*)d_out;

    // ws layout (~81 MiB):
    //   [0,   64M) : bx / hs  bf16  [SEQ][DIM]
    //   [64M, 72M) : w_in     bf16  [DIM][DIM]
    //   [72M, 80M) : c_out    bf16  [DIM][DIM]
    //   [80M, +1M) : chunk carries fp32 [NCHUNK][DIM]
    char*  ws    = (char*)d_ws;
    short* bxh   = (short*)ws;
    short* w_bf  = (short*)(ws + (size_t)64 * 1024 * 1024);
    short* c_bf  = (short*)(ws + (size_t)72 * 1024 * 1024);
    float* blkl  = (float*)(ws + (size_t)80 * 1024 * 1024);
    // xs_bf16 lives in the front 64 MiB of d_out (dead before final GEMM writes it)
    short* xs_bf = (short*)d_out;

    cast_kernel<<<SEQ * DIM / 4 / 256, 256, 0, stream>>>(xs, xs_bf, SEQ * DIM / 4);
    cast_kernel<<<DIM * DIM / 4 / 256, 256, 0, stream>>>(w_in, w_bf, DIM * DIM / 4);
    cast_kernel<<<DIM * DIM / 4 / 256, 256, 0, stream>>>(c_out, c_bf, DIM * DIM / 4);

    dim3 ggrid(DIM / 128, SEQ / 128);   // (16, 128)
    gemm_bt<0><<<ggrid, 256, 0, stream>>>(xs_bf, w_bf, bxh, nullptr, nullptr, nullptr);

    dim3 sgrid(DIM / 1024, NCHUNK);     // (2, 128)
    scan_pass1<<<sgrid, 256, 0, stream>>>(bxh, lam, blkl);
    scan_pass2<<<DIM / 1024, 256, 0, stream>>>(blkl, lam);
    scan_pass3<<<sgrid, 256, 0, stream>>>(bxh, lam, blkl);

    gemm_bt<1><<<ggrid, 256, 0, stream>>>(bxh, c_bf, nullptr, out, xs, dskip);
}